// Round 1
// baseline (29.465 us; speedup 1.0000x reference)
//
#include <hip/hip_runtime.h>
#include <hip/hip_bf16.h>
#include <math.h>

// MultiVariateAttention: out[b,u] = exp(mvn_logpdf(x[b]; mu[u], diag(s[u])))
// B = U = 4096, D = 16, fp32 in/out.
//
// Rewritten as: log2(out) = sum_d x*A1 + sum_d x^2*A2 + bias  (per-u params)
//   A1[u,d] = log2e * mu*w,  A2[u,d] = -0.5*log2e*w,  w = 1/s^2
//   bias[u] = log2e * (-0.5*sum mu^2 w - sum log s - D*0.5*log(2pi))
// then out = exp2(acc)  (single v_exp_f32).

#define TPB 256
#define DD 16
#define UPT 4      // u's per thread -> float4 stores
#define BPB 32     // b rows per block

static constexpr float L2E   = 1.4426950408889634f;   // log2(e)
static constexpr float HL2PI = 0.91893853320467274f;  // 0.5*ln(2*pi)

// P layout: [2*D+1][U]. rows 0..15 = A1[d], 16..31 = A2[d], 32 = bias.
__global__ __launch_bounds__(TPB) void mva_precompute(
    const float* __restrict__ units, const float* __restrict__ attn,
    float* __restrict__ P, int U)
{
    int u = blockIdx.x * TPB + threadIdx.x;
    if (u >= U) return;
    float bn = 0.f;
#pragma unroll
    for (int d = 0; d < DD; ++d) {
        float s  = fmaxf(attn[(size_t)u * DD * DD + d * (DD + 1)], 1e-6f);
        float w  = 1.f / (s * s);
        float mu = units[u * DD + d];
        P[(size_t)d * U + u]        = L2E * mu * w;
        P[(size_t)(DD + d) * U + u] = -0.5f * L2E * w;
        bn += -0.5f * mu * mu * w - logf(s);
    }
    P[(size_t)(2 * DD) * U + u] = L2E * (bn - DD * HL2PI);
}

template <bool USE_WS>
__global__ __launch_bounds__(TPB) void mva_main(
    const float* __restrict__ x,      // [B,1,D]
    const float* __restrict__ P,      // [33][U] when USE_WS
    const float* __restrict__ units,  // raw params when !USE_WS
    const float* __restrict__ attn,
    float* __restrict__ out, int U)
{
    const int u0 = blockIdx.y * (TPB * UPT) + threadIdx.x * UPT;
    const int b0 = blockIdx.x * BPB;

    float a1[UPT][DD], a2[UPT][DD], bias[UPT];

    if (USE_WS) {
#pragma unroll
        for (int d = 0; d < DD; ++d) {
            float4 v = *reinterpret_cast<const float4*>(P + (size_t)d * U + u0);
            a1[0][d] = v.x; a1[1][d] = v.y; a1[2][d] = v.z; a1[3][d] = v.w;
            float4 w = *reinterpret_cast<const float4*>(P + (size_t)(DD + d) * U + u0);
            a2[0][d] = w.x; a2[1][d] = w.y; a2[2][d] = w.z; a2[3][d] = w.w;
        }
        float4 bv = *reinterpret_cast<const float4*>(P + (size_t)(2 * DD) * U + u0);
        bias[0] = bv.x; bias[1] = bv.y; bias[2] = bv.z; bias[3] = bv.w;
    } else {
#pragma unroll
        for (int i = 0; i < UPT; ++i) {
            int u = u0 + i;
            float bn = 0.f;
#pragma unroll
            for (int d = 0; d < DD; ++d) {
                float s  = fmaxf(attn[(size_t)u * DD * DD + d * (DD + 1)], 1e-6f);
                float w  = 1.f / (s * s);
                float mu = units[u * DD + d];
                a1[i][d] = L2E * mu * w;
                a2[i][d] = -0.5f * L2E * w;
                bn += -0.5f * mu * mu * w - logf(s);
            }
            bias[i] = L2E * (bn - DD * HL2PI);
        }
    }

    // Stage x tile (+ squares) in LDS: [BPB][32] = x[0..15], x^2[16..31]
    __shared__ float xs[BPB][2 * DD];
    for (int idx = threadIdx.x; idx < BPB * DD; idx += TPB) {
        int b = idx >> 4, d = idx & 15;
        float v = x[(size_t)(b0 + b) * DD + d];
        xs[b][d]      = v;
        xs[b][DD + d] = v * v;
    }
    __syncthreads();

    for (int b = 0; b < BPB; ++b) {
        float acc[UPT];
#pragma unroll
        for (int i = 0; i < UPT; ++i) acc[i] = bias[i];
#pragma unroll
        for (int j = 0; j < 4; ++j) {
            float4 xv = *reinterpret_cast<const float4*>(&xs[b][4 * j]);
            float4 qv = *reinterpret_cast<const float4*>(&xs[b][DD + 4 * j]);
#pragma unroll
            for (int i = 0; i < UPT; ++i) {
                acc[i] = fmaf(xv.x, a1[i][4 * j + 0], acc[i]);
                acc[i] = fmaf(qv.x, a2[i][4 * j + 0], acc[i]);
                acc[i] = fmaf(xv.y, a1[i][4 * j + 1], acc[i]);
                acc[i] = fmaf(qv.y, a2[i][4 * j + 1], acc[i]);
                acc[i] = fmaf(xv.z, a1[i][4 * j + 2], acc[i]);
                acc[i] = fmaf(qv.z, a2[i][4 * j + 2], acc[i]);
                acc[i] = fmaf(xv.w, a1[i][4 * j + 3], acc[i]);
                acc[i] = fmaf(qv.w, a2[i][4 * j + 3], acc[i]);
            }
        }
        float4 o;
        o.x = __builtin_amdgcn_exp2f(acc[0]);
        o.y = __builtin_amdgcn_exp2f(acc[1]);
        o.z = __builtin_amdgcn_exp2f(acc[2]);
        o.w = __builtin_amdgcn_exp2f(acc[3]);
        *reinterpret_cast<float4*>(out + (size_t)(b0 + b) * U + u0) = o;
    }
}

extern "C" void kernel_launch(void* const* d_in, const int* in_sizes, int n_in,
                              void* d_out, int out_size, void* d_ws, size_t ws_size,
                              hipStream_t stream) {
    const float* x     = (const float*)d_in[0];  // [B,1,D]
    const float* units = (const float*)d_in[1];  // [U,D]
    const float* attn  = (const float*)d_in[2];  // [U,D,D]
    float* out = (float*)d_out;

    const int B = in_sizes[0] / DD;  // 4096
    const int U = in_sizes[1] / DD;  // 4096

    dim3 grid(B / BPB, U / (TPB * UPT));  // (128, 4)
    size_t pbytes = (size_t)(2 * DD + 1) * U * sizeof(float);

    if (ws_size >= pbytes) {
        float* P = (float*)d_ws;
        mva_precompute<<<(U + TPB - 1) / TPB, TPB, 0, stream>>>(units, attn, P, U);
        mva_main<true><<<grid, TPB, 0, stream>>>(x, P, units, attn, out, U);
    } else {
        mva_main<false><<<grid, TPB, 0, stream>>>(x, nullptr, units, attn, out, U);
    }
}